// Round 13
// baseline (174.566 us; speedup 1.0000x reference)
//
#include <hip/hip_runtime.h>
#include <hip/hip_bf16.h>

typedef unsigned short u16;
typedef u16 us4 __attribute__((ext_vector_type(4)));
typedef u16 us8 __attribute__((ext_vector_type(8)));
typedef __bf16 bf16x8 __attribute__((ext_vector_type(8)));
typedef float f32x4 __attribute__((ext_vector_type(4)));

#define NDIM 4096
#define HDIM 2048

__device__ __forceinline__ u16 bfbits(float f) {
    __hip_bfloat16 h = __float2bfloat16(f);
    return __builtin_bit_cast(u16, h);
}
__device__ __forceinline__ float bf2f(u16 b) {
    return __builtin_bit_cast(float, ((unsigned)b) << 16);
}

__device__ __forceinline__ void gload_lds16(const u16* g, u16* l) {
    __builtin_amdgcn_global_load_lds((__attribute__((address_space(1))) void*)g,
                                     (__attribute__((address_space(3))) void*)l,
                                     16, 0, 0);
}

// ---------------------------------------------------------------------------
// Fused prep: blocks [0,2048) generate cos tables; blocks [2048,6144) do the
// transpose+split of X (co-residency overlaps VALU with HBM traffic).
__global__ __launch_bounds__(256) void k_prep(u16* __restrict__ Ce, u16* __restrict__ Co,
                                              const float* __restrict__ X,
                                              u16* __restrict__ Xe, u16* __restrict__ Xo) {
    __shared__ float tile[64][65];
    if (blockIdx.x < 2048) {
        int idx = blockIdx.x * 256 + threadIdx.x;
        int u = idx >> 8;
        int k0 = (idx & 255) * 8;
        unsigned step = (unsigned)(2 * u + 1);
        us8 e, o;
#pragma unroll
        for (int i = 0; i < 8; ++i) {
            unsigned kk = (unsigned)(k0 + i);
            unsigned te = (2u * kk * step) & 16383u;
            unsigned to = ((2u * kk + 1u) * step) & 16383u;
            e[i] = bfbits(cosf((float)te * 3.8349519697141029e-4f)); // 2pi/16384
            o[i] = bfbits(cosf((float)to * 3.8349519697141029e-4f));
        }
        *(us8*)&Ce[(size_t)idx * 8] = e;
        *(us8*)&Co[(size_t)idx * 8] = o;
    } else {
        int b  = blockIdx.x - 2048;
        int bx = (b & 63) * 64;
        int by = (b >> 6) * 64;
        int t  = threadIdx.x;
        int lr = t >> 4, lc = (t & 15) * 4;
#pragma unroll
        for (int r = 0; r < 64; r += 16) {
            float4 v = *(const float4*)&X[(size_t)(by + lr + r) * NDIM + bx + lc];
            tile[lr + r][lc + 0] = v.x;
            tile[lr + r][lc + 1] = v.y;
            tile[lr + r][lc + 2] = v.z;
            tile[lr + r][lc + 3] = v.w;
        }
        __syncthreads();
        int jl = t >> 2;
        int s8 = (t & 3) * 8;
        us8 e, o;
#pragma unroll
        for (int i = 0; i < 8; ++i) {
            e[i] = bfbits(tile[2 * (s8 + i)][jl]);
            o[i] = bfbits(tile[2 * (s8 + i) + 1][jl]);
        }
        size_t base = (size_t)(bx + jl) * HDIM + (by >> 1) + s8;
        *(us8*)&Xe[base] = e;
        *(us8*)&Xo[base] = o;
    }
}

// ---------------------------------------------------------------------------
// Butterfly 1: W[u] = S[u]+D[u], W[4095-u] = S[u]-D[u], column-deinterleaved.
__global__ __launch_bounds__(256) void k_bfly1(const u16* __restrict__ S,
                                               const u16* __restrict__ D,
                                               u16* __restrict__ We,
                                               u16* __restrict__ Wo) {
    int idx = blockIdx.x * 256 + threadIdx.x;
    int u  = idx >> 9;
    int j0 = (idx & 511) * 8;
    us8 s8 = *(const us8*)&S[(size_t)u * NDIM + j0];
    us8 d8 = *(const us8*)&D[(size_t)u * NDIM + j0];
    us4 et, ot, eb, ob;
#pragma unroll
    for (int i = 0; i < 4; ++i) {
        float se = bf2f(s8[2 * i]),     de = bf2f(d8[2 * i]);
        float so = bf2f(s8[2 * i + 1]), dd = bf2f(d8[2 * i + 1]);
        et[i] = bfbits(se + de);  eb[i] = bfbits(se - de);
        ot[i] = bfbits(so + dd);  ob[i] = bfbits(so - dd);
    }
    size_t ct = (size_t)u * HDIM + (j0 >> 1);
    size_t cb = (size_t)(NDIM - 1 - u) * HDIM + (j0 >> 1);
    *(us4*)&We[ct] = et;  *(us4*)&Wo[ct] = ot;
    *(us4*)&We[cb] = eb;  *(us4*)&Wo[cb] = ob;
}

// ---------------------------------------------------------------------------
// Butterfly 2: Y[i][v'] = S2+D2, Y[i][4095-v'] = S2-D2, f32 out.
__global__ __launch_bounds__(256) void k_bfly2(const u16* __restrict__ S2,
                                               const u16* __restrict__ D2,
                                               float* __restrict__ Y) {
    int idx = blockIdx.x * 256 + threadIdx.x;
    int i  = idx >> 8;
    int v0 = (idx & 255) * 8;
    us8 s8 = *(const us8*)&S2[(size_t)i * HDIM + v0];
    us8 d8 = *(const us8*)&D2[(size_t)i * HDIM + v0];
    float sum[8], dif[8];
#pragma unroll
    for (int t = 0; t < 8; ++t) {
        float s = bf2f(s8[t]), d = bf2f(d8[t]);
        sum[t] = s + d;  dif[t] = s - d;
    }
    f32x4 a0, a1, r0, r1;
#pragma unroll
    for (int w = 0; w < 4; ++w) {
        a0[w] = sum[w];  a1[w] = sum[w + 4];
        r0[w] = dif[7 - w];  r1[w] = dif[3 - w];
    }
    float* row = Y + (size_t)i * NDIM;
    *(f32x4*)&row[v0]        = a0;
    *(f32x4*)&row[v0 + 4]    = a1;
    *(f32x4*)&row[4088 - v0] = r0;
    *(f32x4*)&row[4092 - v0] = r1;
}

// ---------------------------------------------------------------------------
// D = A @ B^T, 256x256 tile, BK=64, 8 waves, 3-half-deep counted-vmcnt
// pipeline. r13 = r7 content with phase PAIRS merged: 4 regions of 32 MFMA,
// 8 barriers/iter (was 16). Stage repacking {2,6,2,6}; every overwrite's
// last reader is in the previous region (sealed by its post-MFMA barrier);
// region stage targets disjoint from own reads; vmcnt FIFO simulated:
// WAITV(6) at region 2/4 completes tile t+1 / t+2 exactly. MFMA order per
// accumulator unchanged -> bitwise-same output (canary: absmax 64).
#define BAR() do { asm volatile("" ::: "memory"); __builtin_amdgcn_s_barrier(); \
                   asm volatile("" ::: "memory"); } while (0)
#define WAITV(N) asm volatile("s_waitcnt vmcnt(" #N ")" ::: "memory")

template <int NTK, int LOG_NTN>
__global__ __launch_bounds__(512, 2) void gemm256h(const u16* __restrict__ A0,
                                                   const u16* __restrict__ A1,
                                                   const u16* __restrict__ B0,
                                                   const u16* __restrict__ B1,
                                                   u16* __restrict__ out) {
    constexpr int KD  = NTK * 64;
    constexpr int NTN = 1 << LOG_NTN;
    constexpr int LDC = NTN * 256;
    constexpr int MTILES = 128 >> LOG_NTN;

    __shared__ u16 As[2 * 256 * 64];
    __shared__ u16 Bs[2 * 256 * 64];

    const int tid  = threadIdx.x;
    const int wave = tid >> 6;
    const int lane = tid & 63;

    const int bid = blockIdx.x;
    const int swz = (bid & 7) * 32 + (bid >> 3);   // grid 256, bijective
    const int half = swz >> 7;
    const int r    = swz & 127;
    const int bm   = (r >> LOG_NTN) * 256;
    const int bn   = (r & (NTN - 1)) * 256;

    const u16* A = half ? A1 : A0;
    const u16* B = half ? B1 : B0;
    u16* Cp = out + (size_t)half * MTILES * 256 * LDC;

    const int wr = wave >> 2;
    const int wc = wave & 3;

    const int srow = lane >> 3;
    const int scol = ((lane & 7) ^ srow) << 3;     // pre-swizzled global col offset

    const int fr   = lane & 15;
    const int hi   = lane >> 4;
    const int slot0 = ((hi)     ^ (lane & 7)) << 3;
    const int slot1 = ((hi + 4) ^ (lane & 7)) << 3;
    const int aRow = (wr * 128 + fr) * 64;
    const int bRow = (wc * 64 + fr) * 64;

    f32x4 acc[8][4] = {};
    bf16x8 aR[4][2], b01[2][2], b23[2][2];

#define STAGE_A(TK, H, BOFF)                                                     \
    do {                                                                         \
        const int _tk = (TK) & (NTK - 1);                                        \
        _Pragma("unroll")                                                        \
        for (int q = 0; q < 2; ++q) {                                            \
            const int seg  = wave * 2 + q;                                       \
            const int row0 = (H) * 64 + (seg & 7) * 8 + (seg >> 3) * 128;        \
            const u16* _g = A + (size_t)(bm + row0 + srow) * KD + _tk * 64 + scol; \
            gload_lds16(_g, As + (BOFF) + row0 * 64 + lane * 8);                 \
        }                                                                        \
    } while (0)

#define STAGE_B(TK, H, BOFF)                                                     \
    do {                                                                         \
        const int _tk = (TK) & (NTK - 1);                                        \
        _Pragma("unroll")                                                        \
        for (int q = 0; q < 2; ++q) {                                            \
            const int seg  = wave * 2 + q;                                       \
            const int row0 = (H) * 32 + (seg & 3) * 8 + (seg >> 2) * 64;         \
            const u16* _g = B + (size_t)(bn + row0 + srow) * KD + _tk * 64 + scol; \
            gload_lds16(_g, Bs + (BOFF) + row0 * 64 + lane * 8);                 \
        }                                                                        \
    } while (0)

#define LOAD_A(MB, BOFF)                                                        \
    _Pragma("unroll")                                                           \
    for (int mm = 0; mm < 4; ++mm) {                                            \
        aR[mm][0] = __builtin_bit_cast(bf16x8, *(const us8*)(As + (BOFF) + aRow + ((MB) + mm) * 1024 + slot0)); \
        aR[mm][1] = __builtin_bit_cast(bf16x8, *(const us8*)(As + (BOFF) + aRow + ((MB) + mm) * 1024 + slot1)); \
    }

#define LOAD_B(DST, NB, BOFF)                                                   \
    _Pragma("unroll")                                                           \
    for (int nn = 0; nn < 2; ++nn) {                                            \
        DST[nn][0] = __builtin_bit_cast(bf16x8, *(const us8*)(Bs + (BOFF) + bRow + ((NB) + nn) * 1024 + slot0)); \
        DST[nn][1] = __builtin_bit_cast(bf16x8, *(const us8*)(Bs + (BOFF) + bRow + ((NB) + nn) * 1024 + slot1)); \
    }

// k-OUTER: 8 independent MFMAs between dependent acc updates; per-acc order
// k0-then-k1.
#define MFMA_Q(MB, NB, BREG)                                                    \
    do {                                                                        \
        __builtin_amdgcn_s_setprio(1);                                          \
        _Pragma("unroll")                                                       \
        for (int kk = 0; kk < 2; ++kk)                                          \
            _Pragma("unroll")                                                   \
            for (int mm = 0; mm < 4; ++mm)                                      \
                _Pragma("unroll")                                               \
                for (int nn = 0; nn < 2; ++nn)                                  \
                    acc[(MB)+mm][(NB)+nn] = __builtin_amdgcn_mfma_f32_16x16x32_bf16(aR[mm][kk], BREG[nn][kk], acc[(MB)+mm][(NB)+nn], 0, 0, 0); \
        __builtin_amdgcn_s_setprio(0);                                          \
    } while (0)

    // ---- prologue: 7 halves; WAITV(6)+BAR certifies tile 0 (6 outstanding)
    STAGE_B(0, 0, 0);
    STAGE_A(0, 0, 0);
    STAGE_B(0, 1, 0);
    STAGE_A(0, 1, 0);
    STAGE_B(1, 0, 16384);
    STAGE_A(1, 0, 16384);
    STAGE_B(1, 1, 16384);
    WAITV(6);
    BAR();

    for (int t = 0; t < NTK; t += 2) {
        // region 1 (old ph1+2): reads tile t A03+B01+B23 (buf0);
        //   stage A(t+1)h1'->buf1; MFMA rows0-3 all cols
        LOAD_A(0, 0);
        LOAD_B(b01, 0, 0);
        LOAD_B(b23, 2, 0);
        STAGE_A(t + 1, 1, 16384);
        BAR();
        MFMA_Q(0, 0, b01);
        MFMA_Q(0, 2, b23);
        BAR();
        // region 2 (old ph3+4): reads A47 (buf0);
        //   stage B(t+2)h0', A(t+2)h0', B(t+2)h1' -> buf0 (targets disjoint
        //   from A47 reads); MFMA rows4-7; WAITV(6) completes tile t+1
        LOAD_A(4, 0);
        STAGE_B(t + 2, 0, 0);
        STAGE_A(t + 2, 0, 0);
        STAGE_B(t + 2, 1, 0);
        BAR();
        MFMA_Q(4, 2, b23);
        MFMA_Q(4, 0, b01);
        WAITV(6);
        BAR();
        // region 3 (old ph5+6): reads tile t+1 A03+B01+B23 (buf1);
        //   stage A(t+2)h1'->buf0; MFMA rows0-3
        LOAD_A(0, 16384);
        LOAD_B(b01, 0, 16384);
        LOAD_B(b23, 2, 16384);
        STAGE_A(t + 2, 1, 0);
        BAR();
        MFMA_Q(0, 0, b01);
        MFMA_Q(0, 2, b23);
        BAR();
        // region 4 (old ph7+8): reads A47 (buf1);
        //   stage B(t+3)h0', A(t+3)h0', B(t+3)h1' -> buf1; MFMA rows4-7;
        //   WAITV(6) completes tile t+2
        LOAD_A(4, 16384);
        STAGE_B(t + 3, 0, 16384);
        STAGE_A(t + 3, 0, 16384);
        STAGE_B(t + 3, 1, 16384);
        BAR();
        MFMA_Q(4, 2, b23);
        MFMA_Q(4, 0, b01);
        WAITV(6);
        BAR();
    }

    asm volatile("s_waitcnt vmcnt(0)" ::: "memory");

    const int orow0 = wr * 128 + hi * 4;
    const int ocol0 = bn + wc * 64 + fr;
#pragma unroll
    for (int m = 0; m < 8; ++m)
#pragma unroll
        for (int n = 0; n < 4; ++n) {
            f32x4 v = acc[m][n];
#pragma unroll
            for (int rr = 0; rr < 4; ++rr) {
                size_t off = (size_t)(bm + orow0 + m * 16 + rr) * LDC + (ocol0 + n * 16);
                Cp[off] = bfbits(v[rr]);
            }
        }
#undef STAGE_A
#undef STAGE_B
#undef LOAD_A
#undef LOAD_B
#undef MFMA_Q
}

// ---------------------------------------------------------------------------
extern "C" void kernel_launch(void* const* d_in, const int* in_sizes, int n_in,
                              void* d_out, int out_size, void* d_ws, size_t ws_size,
                              hipStream_t stream) {
    const float* X = (const float*)d_in[0];
    float* Y = (float*)d_out;

    const size_t QM = (size_t)HDIM * HDIM;
    u16* Ce = (u16*)d_ws;
    u16* Co = Ce + QM;
    u16* Xe = Co + QM;
    u16* Xo = Xe + 2 * QM;
    u16* S  = Xo + 2 * QM;
    u16* D  = S + 2 * QM;
    u16* We = Xe;
    u16* Wo = Xo;
    u16* S2 = S;
    u16* D2 = D;

    k_prep<<<6144, 256, 0, stream>>>(Ce, Co, X, Xe, Xo);
    gemm256h<32, 4><<<256, 512, 0, stream>>>(Ce, Co, Xe, Xo, S);
    k_bfly1<<<4096, 256, 0, stream>>>(S, D, We, Wo);
    gemm256h<32, 3><<<256, 512, 0, stream>>>(We, Wo, Ce, Co, S2);
    k_bfly2<<<4096, 256, 0, stream>>>(S2, D2, Y);
}

// Round 14
// 172.038 us; speedup vs baseline: 1.0147x; 1.0147x over previous
//
#include <hip/hip_runtime.h>
#include <hip/hip_bf16.h>

typedef unsigned short u16;
typedef u16 us4 __attribute__((ext_vector_type(4)));
typedef u16 us8 __attribute__((ext_vector_type(8)));
typedef __bf16 bf16x8 __attribute__((ext_vector_type(8)));
typedef float f32x4 __attribute__((ext_vector_type(4)));

#define NDIM 4096
#define HDIM 2048

__device__ __forceinline__ u16 bfbits(float f) {
    __hip_bfloat16 h = __float2bfloat16(f);
    return __builtin_bit_cast(u16, h);
}
__device__ __forceinline__ float bf2f(u16 b) {
    return __builtin_bit_cast(float, ((unsigned)b) << 16);
}

__device__ __forceinline__ void gload_lds16(const u16* g, u16* l) {
    __builtin_amdgcn_global_load_lds((__attribute__((address_space(1))) void*)g,
                                     (__attribute__((address_space(3))) void*)l,
                                     16, 0, 0);
}

#define BAR() do { asm volatile("" ::: "memory"); __builtin_amdgcn_s_barrier(); \
                   asm volatile("" ::: "memory"); } while (0)
#define WAITV(N) asm volatile("s_waitcnt vmcnt(" #N ")" ::: "memory")

// ---------------------------------------------------------------------------
// Fused prep: blocks [0,2048) generate cos tables; blocks [2048,6144) do the
// transpose+split of X (co-residency overlaps VALU with HBM traffic).
__global__ __launch_bounds__(256) void k_prep(u16* __restrict__ Ce, u16* __restrict__ Co,
                                              const float* __restrict__ X,
                                              u16* __restrict__ Xe, u16* __restrict__ Xo) {
    __shared__ float tile[64][65];
    if (blockIdx.x < 2048) {
        int idx = blockIdx.x * 256 + threadIdx.x;
        int u = idx >> 8;
        int k0 = (idx & 255) * 8;
        unsigned step = (unsigned)(2 * u + 1);
        us8 e, o;
#pragma unroll
        for (int i = 0; i < 8; ++i) {
            unsigned kk = (unsigned)(k0 + i);
            unsigned te = (2u * kk * step) & 16383u;
            unsigned to = ((2u * kk + 1u) * step) & 16383u;
            e[i] = bfbits(cosf((float)te * 3.8349519697141029e-4f)); // 2pi/16384
            o[i] = bfbits(cosf((float)to * 3.8349519697141029e-4f));
        }
        *(us8*)&Ce[(size_t)idx * 8] = e;
        *(us8*)&Co[(size_t)idx * 8] = o;
    } else {
        int b  = blockIdx.x - 2048;
        int bx = (b & 63) * 64;
        int by = (b >> 6) * 64;
        int t  = threadIdx.x;
        int lr = t >> 4, lc = (t & 15) * 4;
#pragma unroll
        for (int r = 0; r < 64; r += 16) {
            float4 v = *(const float4*)&X[(size_t)(by + lr + r) * NDIM + bx + lc];
            tile[lr + r][lc + 0] = v.x;
            tile[lr + r][lc + 1] = v.y;
            tile[lr + r][lc + 2] = v.z;
            tile[lr + r][lc + 3] = v.w;
        }
        __syncthreads();
        int jl = t >> 2;
        int s8 = (t & 3) * 8;
        us8 e, o;
#pragma unroll
        for (int i = 0; i < 8; ++i) {
            e[i] = bfbits(tile[2 * (s8 + i)][jl]);
            o[i] = bfbits(tile[2 * (s8 + i) + 1][jl]);
        }
        size_t base = (size_t)(bx + jl) * HDIM + (by >> 1) + s8;
        *(us8*)&Xe[base] = e;
        *(us8*)&Xo[base] = o;
    }
}

// ---------------------------------------------------------------------------
// Butterfly 1: W[u] = S[u]+D[u], W[4095-u] = S[u]-D[u], column-deinterleaved.
__global__ __launch_bounds__(256) void k_bfly1(const u16* __restrict__ S,
                                               const u16* __restrict__ D,
                                               u16* __restrict__ We,
                                               u16* __restrict__ Wo) {
    int idx = blockIdx.x * 256 + threadIdx.x;
    int u  = idx >> 9;
    int j0 = (idx & 511) * 8;
    us8 s8 = *(const us8*)&S[(size_t)u * NDIM + j0];
    us8 d8 = *(const us8*)&D[(size_t)u * NDIM + j0];
    us4 et, ot, eb, ob;
#pragma unroll
    for (int i = 0; i < 4; ++i) {
        float se = bf2f(s8[2 * i]),     de = bf2f(d8[2 * i]);
        float so = bf2f(s8[2 * i + 1]), dd = bf2f(d8[2 * i + 1]);
        et[i] = bfbits(se + de);  eb[i] = bfbits(se - de);
        ot[i] = bfbits(so + dd);  ob[i] = bfbits(so - dd);
    }
    size_t ct = (size_t)u * HDIM + (j0 >> 1);
    size_t cb = (size_t)(NDIM - 1 - u) * HDIM + (j0 >> 1);
    *(us4*)&We[ct] = et;  *(us4*)&Wo[ct] = ot;
    *(us4*)&We[cb] = eb;  *(us4*)&Wo[cb] = ob;
}

// ---------------------------------------------------------------------------
// GEMM1: D = A @ B^T, 256x256 tile, BK=64, 8 waves, 8-phase schedule,
// 3-half-deep counted-vmcnt pipeline (exact r7 structure, throttle removed).
template <int NTK, int LOG_NTN>
__global__ __launch_bounds__(512, 2) void gemm256h(const u16* __restrict__ A0,
                                                   const u16* __restrict__ A1,
                                                   const u16* __restrict__ B0,
                                                   const u16* __restrict__ B1,
                                                   u16* __restrict__ out) {
    constexpr int KD  = NTK * 64;
    constexpr int NTN = 1 << LOG_NTN;
    constexpr int LDC = NTN * 256;
    constexpr int MTILES = 128 >> LOG_NTN;

    __shared__ u16 As[2 * 256 * 64];
    __shared__ u16 Bs[2 * 256 * 64];

    const int tid  = threadIdx.x;
    const int wave = tid >> 6;
    const int lane = tid & 63;

    const int bid = blockIdx.x;
    const int swz = (bid & 7) * 32 + (bid >> 3);
    const int half = swz >> 7;
    const int r    = swz & 127;
    const int bm   = (r >> LOG_NTN) * 256;
    const int bn   = (r & (NTN - 1)) * 256;

    const u16* A = half ? A1 : A0;
    const u16* B = half ? B1 : B0;
    u16* Cp = out + (size_t)half * MTILES * 256 * LDC;

    const int wr = wave >> 2;
    const int wc = wave & 3;

    const int srow = lane >> 3;
    const int scol = ((lane & 7) ^ srow) << 3;

    const int fr   = lane & 15;
    const int hi   = lane >> 4;
    const int slot0 = ((hi)     ^ (lane & 7)) << 3;
    const int slot1 = ((hi + 4) ^ (lane & 7)) << 3;
    const int aRow = (wr * 128 + fr) * 64;
    const int bRow = (wc * 64 + fr) * 64;

    f32x4 acc[8][4] = {};
    bf16x8 aR[4][2], b01[2][2], b23[2][2];

#define STAGE_A(TK, H, BOFF)                                                     \
    do {                                                                         \
        const int _tk = (TK) & (NTK - 1);                                        \
        _Pragma("unroll")                                                        \
        for (int q = 0; q < 2; ++q) {                                            \
            const int seg  = wave * 2 + q;                                       \
            const int row0 = (H) * 64 + (seg & 7) * 8 + (seg >> 3) * 128;        \
            const u16* _g = A + (size_t)(bm + row0 + srow) * KD + _tk * 64 + scol; \
            gload_lds16(_g, As + (BOFF) + row0 * 64 + lane * 8);                 \
        }                                                                        \
    } while (0)

#define STAGE_B(TK, H, BOFF)                                                     \
    do {                                                                         \
        const int _tk = (TK) & (NTK - 1);                                        \
        _Pragma("unroll")                                                        \
        for (int q = 0; q < 2; ++q) {                                            \
            const int seg  = wave * 2 + q;                                       \
            const int row0 = (H) * 32 + (seg & 3) * 8 + (seg >> 2) * 64;         \
            const u16* _g = B + (size_t)(bn + row0 + srow) * KD + _tk * 64 + scol; \
            gload_lds16(_g, Bs + (BOFF) + row0 * 64 + lane * 8);                 \
        }                                                                        \
    } while (0)

#define LOAD_A(MB, BOFF)                                                        \
    _Pragma("unroll")                                                           \
    for (int mm = 0; mm < 4; ++mm) {                                            \
        aR[mm][0] = __builtin_bit_cast(bf16x8, *(const us8*)(As + (BOFF) + aRow + ((MB) + mm) * 1024 + slot0)); \
        aR[mm][1] = __builtin_bit_cast(bf16x8, *(const us8*)(As + (BOFF) + aRow + ((MB) + mm) * 1024 + slot1)); \
    }

#define LOAD_B(DST, NB, BOFF)                                                   \
    _Pragma("unroll")                                                           \
    for (int nn = 0; nn < 2; ++nn) {                                            \
        DST[nn][0] = __builtin_bit_cast(bf16x8, *(const us8*)(Bs + (BOFF) + bRow + ((NB) + nn) * 1024 + slot0)); \
        DST[nn][1] = __builtin_bit_cast(bf16x8, *(const us8*)(Bs + (BOFF) + bRow + ((NB) + nn) * 1024 + slot1)); \
    }

#define MFMA_Q(MB, NB, BREG)                                                    \
    do {                                                                        \
        __builtin_amdgcn_s_setprio(1);                                          \
        _Pragma("unroll")                                                       \
        for (int kk = 0; kk < 2; ++kk)                                          \
            _Pragma("unroll")                                                   \
            for (int mm = 0; mm < 4; ++mm)                                      \
                _Pragma("unroll")                                               \
                for (int nn = 0; nn < 2; ++nn)                                  \
                    acc[(MB)+mm][(NB)+nn] = __builtin_amdgcn_mfma_f32_16x16x32_bf16(aR[mm][kk], BREG[nn][kk], acc[(MB)+mm][(NB)+nn], 0, 0, 0); \
        __builtin_amdgcn_s_setprio(0);                                          \
    } while (0)

    STAGE_B(0, 0, 0);
    STAGE_A(0, 0, 0);
    STAGE_B(0, 1, 0);
    STAGE_A(0, 1, 0);
    STAGE_B(1, 0, 16384);
    STAGE_A(1, 0, 16384);
    STAGE_B(1, 1, 16384);
    WAITV(6);
    BAR();

    for (int t = 0; t < NTK; t += 2) {
        LOAD_A(0, 0);
        LOAD_B(b01, 0, 0);
        STAGE_A(t + 1, 1, 16384);
        BAR();
        MFMA_Q(0, 0, b01);
        BAR();
        LOAD_B(b23, 2, 0);
        STAGE_B(t + 2, 0, 0);
        BAR();
        MFMA_Q(0, 2, b23);
        BAR();
        LOAD_A(4, 0);
        STAGE_A(t + 2, 0, 0);
        BAR();
        MFMA_Q(4, 2, b23);
        BAR();
        STAGE_B(t + 2, 1, 0);
        BAR();
        MFMA_Q(4, 0, b01);
        WAITV(6);
        BAR();
        LOAD_A(0, 16384);
        LOAD_B(b01, 0, 16384);
        STAGE_A(t + 2, 1, 0);
        BAR();
        MFMA_Q(0, 0, b01);
        BAR();
        LOAD_B(b23, 2, 16384);
        STAGE_B(t + 3, 0, 16384);
        BAR();
        MFMA_Q(0, 2, b23);
        BAR();
        LOAD_A(4, 16384);
        STAGE_A(t + 3, 0, 16384);
        BAR();
        MFMA_Q(4, 2, b23);
        BAR();
        STAGE_B(t + 3, 1, 16384);
        BAR();
        MFMA_Q(4, 0, b01);
        WAITV(6);
        BAR();
    }

    asm volatile("s_waitcnt vmcnt(0)" ::: "memory");

    const int orow0 = wr * 128 + hi * 4;
    const int ocol0 = bn + wc * 64 + fr;
#pragma unroll
    for (int m = 0; m < 8; ++m)
#pragma unroll
        for (int n = 0; n < 4; ++n) {
            f32x4 v = acc[m][n];
#pragma unroll
            for (int rr = 0; rr < 4; ++rr) {
                size_t off = (size_t)(bm + orow0 + m * 16 + rr) * LDC + (ocol0 + n * 16);
                Cp[off] = bfbits(v[rr]);
            }
        }
#undef STAGE_A
#undef STAGE_B
#undef LOAD_A
#undef LOAD_B
#undef MFMA_Q
}

// ---------------------------------------------------------------------------
// gemmY: fused GEMM2 + butterfly-2.
// Each block: output tile rows i in [bi,bi+256), cols v' in [bv,bv+128).
// acc_S = We-panel @ Ce-panel^T, acc_D = Wo @ Co^T over K=2048;
// epilogue: Y[i][v'] = S+D, Y[i][4095-v'] = S-D (f32, no intermediate).
// Schedule: 64 sub-tiles (tau even=S(k), odd=D(k)), 3-buffer LDS ring
// (48 KB each: A 256x64 + B 128x64), 2 phases per sub-tile (16 MFMA each),
// stage tau+2 during tau, WAITV(6) per sub-tile at P1-end pre-BAR
// (cross-wave certification), body = 6 sub-tiles x10 + 4-sub-tile tail.
__global__ __launch_bounds__(512, 2) void gemmY(const u16* __restrict__ We,
                                                const u16* __restrict__ Wo,
                                                const u16* __restrict__ Ce,
                                                const u16* __restrict__ Co,
                                                float* __restrict__ Y) {
    constexpr int KD = 2048;
    constexpr int BUF0 = 0, BUF1 = 24576, BUF2 = 49152;   // elem offsets, 48KB each
    __shared__ u16 LDS[3 * 24576];                        // 144 KB

    const int tid  = threadIdx.x;
    const int wave = tid >> 6;
    const int lane = tid & 63;

    const int bid = blockIdx.x;
    const int swz = (bid & 7) * 32 + (bid >> 3);   // grid 256, bijective
    const int bi  = (swz >> 4) * 256;              // 16 row-tiles
    const int bv  = (swz & 15) * 128;              // 16 col-tiles

    const int wr = wave >> 2;    // 0..1 -> 128 rows
    const int wc = wave & 3;     // 0..3 -> 32 cols

    const int srow = lane >> 3;
    const int scol = ((lane & 7) ^ srow) << 3;     // pre-swizzled source col offset

    const int fr   = lane & 15;
    const int hi   = lane >> 4;
    const int slot0 = ((hi)     ^ (lane & 7)) << 3;
    const int slot1 = ((hi + 4) ^ (lane & 7)) << 3;
    const int aRow = (wr * 128 + fr) * 64;         // within A region
    const int bRow = (wc * 32 + fr) * 64;          // within B region

    f32x4 accS[8][2] = {}, accD[8][2] = {};
    bf16x8 aR[4][2], bb[2][2];

// stage full A sub-tile (256 rows x 64 k): 4 loads/wave
#define STAGE_AY(GP, TK, BUF)                                                   \
    do {                                                                        \
        _Pragma("unroll")                                                       \
        for (int q = 0; q < 4; ++q) {                                           \
            const int seg = wave * 4 + q;                                       \
            const u16* _g = (GP) + (size_t)(bi + seg * 8 + srow) * KD + (TK) * 64 + scol; \
            gload_lds16(_g, LDS + (BUF) + seg * 512 + lane * 8);                \
        }                                                                       \
    } while (0)

// stage full B sub-tile (128 rows x 64 k): 2 loads/wave
#define STAGE_BY(GP, TK, BUF)                                                   \
    do {                                                                        \
        _Pragma("unroll")                                                       \
        for (int q = 0; q < 2; ++q) {                                           \
            const int seg = wave * 2 + q;                                       \
            const u16* _g = (GP) + (size_t)(bv + seg * 8 + srow) * KD + (TK) * 64 + scol; \
            gload_lds16(_g, LDS + (BUF) + 16384 + seg * 512 + lane * 8);        \
        }                                                                       \
    } while (0)

#define LOAD_AY(MB, BUF)                                                        \
    _Pragma("unroll")                                                           \
    for (int mm = 0; mm < 4; ++mm) {                                            \
        aR[mm][0] = __builtin_bit_cast(bf16x8, *(const us8*)(LDS + (BUF) + aRow + ((MB) + mm) * 1024 + slot0)); \
        aR[mm][1] = __builtin_bit_cast(bf16x8, *(const us8*)(LDS + (BUF) + aRow + ((MB) + mm) * 1024 + slot1)); \
    }

#define LOAD_BY(BUF)                                                            \
    _Pragma("unroll")                                                           \
    for (int nn = 0; nn < 2; ++nn) {                                            \
        bb[nn][0] = __builtin_bit_cast(bf16x8, *(const us8*)(LDS + (BUF) + 16384 + bRow + nn * 1024 + slot0)); \
        bb[nn][1] = __builtin_bit_cast(bf16x8, *(const us8*)(LDS + (BUF) + 16384 + bRow + nn * 1024 + slot1)); \
    }

#define MFMA16(ACC, MB)                                                         \
    do {                                                                        \
        __builtin_amdgcn_s_setprio(1);                                          \
        _Pragma("unroll")                                                       \
        for (int kk = 0; kk < 2; ++kk)                                          \
            _Pragma("unroll")                                                   \
            for (int mm = 0; mm < 4; ++mm)                                      \
                _Pragma("unroll")                                               \
                for (int nn = 0; nn < 2; ++nn)                                  \
                    ACC[(MB)+mm][nn] = __builtin_amdgcn_mfma_f32_16x16x32_bf16(aR[mm][kk], bb[nn][kk], ACC[(MB)+mm][nn], 0, 0, 0); \
        __builtin_amdgcn_s_setprio(0);                                          \
    } while (0)

// one sub-tile: P0 {reads A03+B, stage A(tau+2), MFMA m0-3},
//               P1 {reads A47, stage B(tau+2), MFMA m4-7, WAITV(6)}
#define SUBTILE(ACC, BUF, BUFN, GA, GB, TKN)                                    \
    do {                                                                        \
        LOAD_AY(0, BUF);                                                        \
        LOAD_BY(BUF);                                                           \
        STAGE_AY(GA, TKN, BUFN);                                                \
        BAR();                                                                  \
        MFMA16(ACC, 0);                                                         \
        BAR();                                                                  \
        LOAD_AY(4, BUF);                                                        \
        STAGE_BY(GB, TKN, BUFN);                                                \
        BAR();                                                                  \
        MFMA16(ACC, 4);                                                         \
        WAITV(6);                                                               \
        BAR();                                                                  \
    } while (0)

    // prologue: stage tau0 = S(0)->buf0, tau1 = D(0)->buf1; certify tau0
    STAGE_AY(We, 0, BUF0);
    STAGE_BY(Ce, 0, BUF0);
    STAGE_AY(Wo, 0, BUF1);
    STAGE_BY(Co, 0, BUF1);
    WAITV(6);
    BAR();

    // body: 6 sub-tiles (3 k-indices) per iteration; ring 0,1,2
    for (int t = 0; t < 30; t += 3) {
        SUBTILE(accS, BUF0, BUF2, We, Ce, (t + 1));        // tau=2t   S(t)
        SUBTILE(accD, BUF1, BUF0, Wo, Co, (t + 1));        // tau=2t+1 D(t)
        SUBTILE(accS, BUF2, BUF1, We, Ce, (t + 2));        // S(t+1)
        SUBTILE(accD, BUF0, BUF2, Wo, Co, (t + 2));        // D(t+1)
        SUBTILE(accS, BUF1, BUF0, We, Ce, (t + 3) & 31);   // S(t+2)
        SUBTILE(accD, BUF2, BUF1, Wo, Co, (t + 3) & 31);   // D(t+2)
    }
    // tail: k=30,31 (tau=60..63; ring continues 0,1,2,0; stage wraps to k=0)
    SUBTILE(accS, BUF0, BUF2, We, Ce, 31);
    SUBTILE(accD, BUF1, BUF0, Wo, Co, 31);
    SUBTILE(accS, BUF2, BUF1, We, Ce, 0);
    SUBTILE(accD, BUF0, BUF2, Wo, Co, 0);

    asm volatile("s_waitcnt vmcnt(0)" ::: "memory");

    // epilogue: butterfly write, f32
    const int orow0 = bi + wr * 128 + hi * 4;
    const int ocol0 = bv + wc * 32 + fr;
#pragma unroll
    for (int m = 0; m < 8; ++m)
#pragma unroll
        for (int n = 0; n < 2; ++n) {
            f32x4 s = accS[m][n], d = accD[m][n];
#pragma unroll
            for (int rr = 0; rr < 4; ++rr) {
                int row = orow0 + m * 16 + rr;
                int vp  = ocol0 + n * 16;
                Y[(size_t)row * NDIM + vp]            = s[rr] + d[rr];
                Y[(size_t)row * NDIM + (NDIM - 1 - vp)] = s[rr] - d[rr];
            }
        }
#undef STAGE_AY
#undef STAGE_BY
#undef LOAD_AY
#undef LOAD_BY
#undef MFMA16
#undef SUBTILE
}

// ---------------------------------------------------------------------------
extern "C" void kernel_launch(void* const* d_in, const int* in_sizes, int n_in,
                              void* d_out, int out_size, void* d_ws, size_t ws_size,
                              hipStream_t stream) {
    const float* X = (const float*)d_in[0];
    float* Y = (float*)d_out;

    const size_t QM = (size_t)HDIM * HDIM;
    u16* Ce = (u16*)d_ws;
    u16* Co = Ce + QM;
    u16* Xe = Co + QM;
    u16* Xo = Xe + 2 * QM;
    u16* S  = Xo + 2 * QM;
    u16* D  = S + 2 * QM;
    u16* We = Xe;     // alias over dead Xe
    u16* Wo = Xo;     // alias over dead Xo

    k_prep<<<6144, 256, 0, stream>>>(Ce, Co, X, Xe, Xo);
    gemm256h<32, 4><<<256, 512, 0, stream>>>(Ce, Co, Xe, Xo, S);
    k_bfly1<<<4096, 256, 0, stream>>>(S, D, We, Wo);
    gemmY<<<256, 512, 0, stream>>>(We, Wo, Ce, Co, Y);
}

// Round 15
// 171.209 us; speedup vs baseline: 1.0196x; 1.0048x over previous
//
#include <hip/hip_runtime.h>
#include <hip/hip_bf16.h>

typedef unsigned short u16;
typedef u16 us4 __attribute__((ext_vector_type(4)));
typedef u16 us8 __attribute__((ext_vector_type(8)));
typedef __bf16 bf16x8 __attribute__((ext_vector_type(8)));
typedef float f32x4 __attribute__((ext_vector_type(4)));

#define NDIM 4096
#define HDIM 2048

__device__ __forceinline__ u16 bfbits(float f) {
    __hip_bfloat16 h = __float2bfloat16(f);
    return __builtin_bit_cast(u16, h);
}
__device__ __forceinline__ float bf2f(u16 b) {
    return __builtin_bit_cast(float, ((unsigned)b) << 16);
}

__device__ __forceinline__ void gload_lds16(const u16* g, u16* l) {
    __builtin_amdgcn_global_load_lds((__attribute__((address_space(1))) void*)g,
                                     (__attribute__((address_space(3))) void*)l,
                                     16, 0, 0);
}

#define BAR() do { asm volatile("" ::: "memory"); __builtin_amdgcn_s_barrier(); \
                   asm volatile("" ::: "memory"); } while (0)
#define WAITV(N) asm volatile("s_waitcnt vmcnt(" #N ")" ::: "memory")

// ---------------------------------------------------------------------------
// Fused prep: blocks [0,2048) generate cos tables; blocks [2048,6144) do the
// transpose+split of X (co-residency overlaps VALU with HBM traffic).
__global__ __launch_bounds__(256) void k_prep(u16* __restrict__ Ce, u16* __restrict__ Co,
                                              const float* __restrict__ X,
                                              u16* __restrict__ Xe, u16* __restrict__ Xo) {
    __shared__ float tile[64][65];
    if (blockIdx.x < 2048) {
        int idx = blockIdx.x * 256 + threadIdx.x;
        int u = idx >> 8;
        int k0 = (idx & 255) * 8;
        unsigned step = (unsigned)(2 * u + 1);
        us8 e, o;
#pragma unroll
        for (int i = 0; i < 8; ++i) {
            unsigned kk = (unsigned)(k0 + i);
            unsigned te = (2u * kk * step) & 16383u;
            unsigned to = ((2u * kk + 1u) * step) & 16383u;
            e[i] = bfbits(cosf((float)te * 3.8349519697141029e-4f)); // 2pi/16384
            o[i] = bfbits(cosf((float)to * 3.8349519697141029e-4f));
        }
        *(us8*)&Ce[(size_t)idx * 8] = e;
        *(us8*)&Co[(size_t)idx * 8] = o;
    } else {
        int b  = blockIdx.x - 2048;
        int bx = (b & 63) * 64;
        int by = (b >> 6) * 64;
        int t  = threadIdx.x;
        int lr = t >> 4, lc = (t & 15) * 4;
#pragma unroll
        for (int r = 0; r < 64; r += 16) {
            float4 v = *(const float4*)&X[(size_t)(by + lr + r) * NDIM + bx + lc];
            tile[lr + r][lc + 0] = v.x;
            tile[lr + r][lc + 1] = v.y;
            tile[lr + r][lc + 2] = v.z;
            tile[lr + r][lc + 3] = v.w;
        }
        __syncthreads();
        int jl = t >> 2;
        int s8 = (t & 3) * 8;
        us8 e, o;
#pragma unroll
        for (int i = 0; i < 8; ++i) {
            e[i] = bfbits(tile[2 * (s8 + i)][jl]);
            o[i] = bfbits(tile[2 * (s8 + i) + 1][jl]);
        }
        size_t base = (size_t)(bx + jl) * HDIM + (by >> 1) + s8;
        *(us8*)&Xe[base] = e;
        *(us8*)&Xo[base] = o;
    }
}

// ---------------------------------------------------------------------------
// Butterfly 1: W[u] = S[u]+D[u], W[4095-u] = S[u]-D[u], column-deinterleaved.
__global__ __launch_bounds__(256) void k_bfly1(const u16* __restrict__ S,
                                               const u16* __restrict__ D,
                                               u16* __restrict__ We,
                                               u16* __restrict__ Wo) {
    int idx = blockIdx.x * 256 + threadIdx.x;
    int u  = idx >> 9;
    int j0 = (idx & 511) * 8;
    us8 s8 = *(const us8*)&S[(size_t)u * NDIM + j0];
    us8 d8 = *(const us8*)&D[(size_t)u * NDIM + j0];
    us4 et, ot, eb, ob;
#pragma unroll
    for (int i = 0; i < 4; ++i) {
        float se = bf2f(s8[2 * i]),     de = bf2f(d8[2 * i]);
        float so = bf2f(s8[2 * i + 1]), dd = bf2f(d8[2 * i + 1]);
        et[i] = bfbits(se + de);  eb[i] = bfbits(se - de);
        ot[i] = bfbits(so + dd);  ob[i] = bfbits(so - dd);
    }
    size_t ct = (size_t)u * HDIM + (j0 >> 1);
    size_t cb = (size_t)(NDIM - 1 - u) * HDIM + (j0 >> 1);
    *(us4*)&We[ct] = et;  *(us4*)&Wo[ct] = ot;
    *(us4*)&We[cb] = eb;  *(us4*)&Wo[cb] = ob;
}

// ---------------------------------------------------------------------------
// Butterfly 2: Y[i][v'] = S2+D2, Y[i][4095-v'] = S2-D2, f32 out.
__global__ __launch_bounds__(256) void k_bfly2(const u16* __restrict__ S2,
                                               const u16* __restrict__ D2,
                                               float* __restrict__ Y) {
    int idx = blockIdx.x * 256 + threadIdx.x;
    int i  = idx >> 8;
    int v0 = (idx & 255) * 8;
    us8 s8 = *(const us8*)&S2[(size_t)i * HDIM + v0];
    us8 d8 = *(const us8*)&D2[(size_t)i * HDIM + v0];
    float sum[8], dif[8];
#pragma unroll
    for (int t = 0; t < 8; ++t) {
        float s = bf2f(s8[t]), d = bf2f(d8[t]);
        sum[t] = s + d;  dif[t] = s - d;
    }
    f32x4 a0, a1, r0, r1;
#pragma unroll
    for (int w = 0; w < 4; ++w) {
        a0[w] = sum[w];  a1[w] = sum[w + 4];
        r0[w] = dif[7 - w];  r1[w] = dif[3 - w];
    }
    float* row = Y + (size_t)i * NDIM;
    *(f32x4*)&row[v0]        = a0;
    *(f32x4*)&row[v0 + 4]    = a1;
    *(f32x4*)&row[4088 - v0] = r0;
    *(f32x4*)&row[4092 - v0] = r1;
}

// ---------------------------------------------------------------------------
// D = A @ B^T, 256x256 tile, BK=64, 8 waves, 8-phase schedule, 3-half-deep
// counted-vmcnt pipeline (r7-exact structure -- the session's proven local
// optimum: 66.0us @ 4096x4096x2048, ~1041 TF, MfmaUtil ~42, 0 bank conflicts).
template <int NTK, int LOG_NTN>
__global__ __launch_bounds__(512, 2) void gemm256h(const u16* __restrict__ A0,
                                                   const u16* __restrict__ A1,
                                                   const u16* __restrict__ B0,
                                                   const u16* __restrict__ B1,
                                                   u16* __restrict__ out) {
    constexpr int KD  = NTK * 64;
    constexpr int NTN = 1 << LOG_NTN;
    constexpr int LDC = NTN * 256;
    constexpr int MTILES = 128 >> LOG_NTN;

    __shared__ u16 As[2 * 256 * 64];
    __shared__ u16 Bs[2 * 256 * 64];

    const int tid  = threadIdx.x;
    const int wave = tid >> 6;
    const int lane = tid & 63;

    const int bid = blockIdx.x;
    const int swz = (bid & 7) * 32 + (bid >> 3);   // grid 256, bijective
    const int half = swz >> 7;
    const int r    = swz & 127;
    const int bm   = (r >> LOG_NTN) * 256;
    const int bn   = (r & (NTN - 1)) * 256;

    const u16* A = half ? A1 : A0;
    const u16* B = half ? B1 : B0;
    u16* Cp = out + (size_t)half * MTILES * 256 * LDC;

    const int wr = wave >> 2;
    const int wc = wave & 3;

    const int srow = lane >> 3;
    const int scol = ((lane & 7) ^ srow) << 3;     // pre-swizzled global col offset

    const int fr   = lane & 15;
    const int hi   = lane >> 4;
    const int slot0 = ((hi)     ^ (lane & 7)) << 3;
    const int slot1 = ((hi + 4) ^ (lane & 7)) << 3;
    const int aRow = (wr * 128 + fr) * 64;
    const int bRow = (wc * 64 + fr) * 64;

    f32x4 acc[8][4] = {};
    bf16x8 aR[4][2], b01[2][2], b23[2][2];

#define STAGE_A(TK, H, BOFF)                                                     \
    do {                                                                         \
        const int _tk = (TK) & (NTK - 1);                                        \
        _Pragma("unroll")                                                        \
        for (int q = 0; q < 2; ++q) {                                            \
            const int seg  = wave * 2 + q;                                       \
            const int row0 = (H) * 64 + (seg & 7) * 8 + (seg >> 3) * 128;        \
            const u16* _g = A + (size_t)(bm + row0 + srow) * KD + _tk * 64 + scol; \
            gload_lds16(_g, As + (BOFF) + row0 * 64 + lane * 8);                 \
        }                                                                        \
    } while (0)

#define STAGE_B(TK, H, BOFF)                                                     \
    do {                                                                         \
        const int _tk = (TK) & (NTK - 1);                                        \
        _Pragma("unroll")                                                        \
        for (int q = 0; q < 2; ++q) {                                            \
            const int seg  = wave * 2 + q;                                       \
            const int row0 = (H) * 32 + (seg & 3) * 8 + (seg >> 2) * 64;         \
            const u16* _g = B + (size_t)(bn + row0 + srow) * KD + _tk * 64 + scol; \
            gload_lds16(_g, Bs + (BOFF) + row0 * 64 + lane * 8);                 \
        }                                                                        \
    } while (0)

#define LOAD_A(MB, BOFF)                                                        \
    _Pragma("unroll")                                                           \
    for (int mm = 0; mm < 4; ++mm) {                                            \
        aR[mm][0] = __builtin_bit_cast(bf16x8, *(const us8*)(As + (BOFF) + aRow + ((MB) + mm) * 1024 + slot0)); \
        aR[mm][1] = __builtin_bit_cast(bf16x8, *(const us8*)(As + (BOFF) + aRow + ((MB) + mm) * 1024 + slot1)); \
    }

#define LOAD_B(DST, NB, BOFF)                                                   \
    _Pragma("unroll")                                                           \
    for (int nn = 0; nn < 2; ++nn) {                                            \
        DST[nn][0] = __builtin_bit_cast(bf16x8, *(const us8*)(Bs + (BOFF) + bRow + ((NB) + nn) * 1024 + slot0)); \
        DST[nn][1] = __builtin_bit_cast(bf16x8, *(const us8*)(Bs + (BOFF) + bRow + ((NB) + nn) * 1024 + slot1)); \
    }

// k-OUTER: 8 independent MFMAs between dependent acc updates; per-acc order
// k0-then-k1.
#define MFMA_Q(MB, NB, BREG)                                                    \
    do {                                                                        \
        __builtin_amdgcn_s_setprio(1);                                          \
        _Pragma("unroll")                                                       \
        for (int kk = 0; kk < 2; ++kk)                                          \
            _Pragma("unroll")                                                   \
            for (int mm = 0; mm < 4; ++mm)                                      \
                _Pragma("unroll")                                               \
                for (int nn = 0; nn < 2; ++nn)                                  \
                    acc[(MB)+mm][(NB)+nn] = __builtin_amdgcn_mfma_f32_16x16x32_bf16(aR[mm][kk], BREG[nn][kk], acc[(MB)+mm][(NB)+nn], 0, 0, 0); \
        __builtin_amdgcn_s_setprio(0);                                          \
    } while (0)

    // ---- prologue: 7 halves, steady-state mimic; vmcnt(6) completes tile 0
    STAGE_B(0, 0, 0);
    STAGE_A(0, 0, 0);
    STAGE_B(0, 1, 0);
    STAGE_A(0, 1, 0);
    STAGE_B(1, 0, 16384);
    STAGE_A(1, 0, 16384);
    STAGE_B(1, 1, 16384);
    WAITV(6);
    BAR();

    for (int t = 0; t < NTK; t += 2) {
        // ph1: compute t(buf0) q(m0-3,n0-1); stage A(t+1)h1' -> buf1
        LOAD_A(0, 0);
        LOAD_B(b01, 0, 0);
        STAGE_A(t + 1, 1, 16384);
        BAR();
        MFMA_Q(0, 0, b01);
        BAR();
        // ph2: q(m0-3,n2-3); stage B(t+2)h0' -> buf0
        LOAD_B(b23, 2, 0);
        STAGE_B(t + 2, 0, 0);
        BAR();
        MFMA_Q(0, 2, b23);
        BAR();
        // ph3: q(m4-7,n2-3); stage A(t+2)h0' -> buf0
        LOAD_A(4, 0);
        STAGE_A(t + 2, 0, 0);
        BAR();
        MFMA_Q(4, 2, b23);
        BAR();
        // ph4: q(m4-7,n0-1); stage B(t+2)h1' -> buf0; vmcnt(6) completes tile t+1
        STAGE_B(t + 2, 1, 0);
        BAR();
        MFMA_Q(4, 0, b01);
        WAITV(6);
        BAR();
        // ph5: compute t+1(buf1) q(m0-3,n0-1); stage A(t+2)h1' -> buf0
        LOAD_A(0, 16384);
        LOAD_B(b01, 0, 16384);
        STAGE_A(t + 2, 1, 0);
        BAR();
        MFMA_Q(0, 0, b01);
        BAR();
        // ph6: q(m0-3,n2-3); stage B(t+3)h0' -> buf1
        LOAD_B(b23, 2, 16384);
        STAGE_B(t + 3, 0, 16384);
        BAR();
        MFMA_Q(0, 2, b23);
        BAR();
        // ph7: q(m4-7,n2-3); stage A(t+3)h0' -> buf1
        LOAD_A(4, 16384);
        STAGE_A(t + 3, 0, 16384);
        BAR();
        MFMA_Q(4, 2, b23);
        BAR();
        // ph8: q(m4-7,n0-1); stage B(t+3)h1' -> buf1; vmcnt(6) completes tile t+2
        STAGE_B(t + 3, 1, 16384);
        BAR();
        MFMA_Q(4, 0, b01);
        WAITV(6);
        BAR();
    }

    asm volatile("s_waitcnt vmcnt(0)" ::: "memory");

    const int orow0 = wr * 128 + hi * 4;
    const int ocol0 = bn + wc * 64 + fr;
#pragma unroll
    for (int m = 0; m < 8; ++m)
#pragma unroll
        for (int n = 0; n < 4; ++n) {
            f32x4 v = acc[m][n];
#pragma unroll
            for (int rr = 0; rr < 4; ++rr) {
                size_t off = (size_t)(bm + orow0 + m * 16 + rr) * LDC + (ocol0 + n * 16);
                Cp[off] = bfbits(v[rr]);
            }
        }
#undef STAGE_A
#undef STAGE_B
#undef LOAD_A
#undef LOAD_B
#undef MFMA_Q
}

// ---------------------------------------------------------------------------
extern "C" void kernel_launch(void* const* d_in, const int* in_sizes, int n_in,
                              void* d_out, int out_size, void* d_ws, size_t ws_size,
                              hipStream_t stream) {
    const float* X = (const float*)d_in[0];
    float* Y = (float*)d_out;

    const size_t QM = (size_t)HDIM * HDIM;
    u16* Ce = (u16*)d_ws;
    u16* Co = Ce + QM;
    u16* Xe = Co + QM;
    u16* Xo = Xe + 2 * QM;
    u16* S  = Xo + 2 * QM;
    u16* D  = S + 2 * QM;
    u16* We = Xe;     // alias over dead Xe
    u16* Wo = Xo;     // alias over dead Xo
    u16* S2 = S;      // alias over dead S
    u16* D2 = D;      // alias over dead D

    k_prep<<<6144, 256, 0, stream>>>(Ce, Co, X, Xe, Xo);
    // GEMM1: S = Ce @ Xe^T, D = Co @ Xo^T   (M=2048, N=4096, K=2048)
    gemm256h<32, 4><<<256, 512, 0, stream>>>(Ce, Co, Xe, Xo, S);
    k_bfly1<<<4096, 256, 0, stream>>>(S, D, We, Wo);
    // GEMM2: S2 = We @ Ce^T, D2 = Wo @ Co^T (M=4096, N=2048, K=2048)
    gemm256h<32, 3><<<256, 512, 0, stream>>>(We, Wo, Ce, Co, S2);
    k_bfly2<<<4096, 256, 0, stream>>>(S2, D2, Y);
}